// Round 6
// baseline (1026.042 us; speedup 1.0000x reference)
//
#include <hip/hip_runtime.h>
#include <math.h>

#define Bn 4096
#define Dn 1024
#define Cn 11003
#define Cpad 11008
#define NCTL 86
#define NQ 9
#define NT 32
#define NTRI 528  // NT*(NT+1)/2

typedef __attribute__((ext_vector_type(8))) short bf16x8;
typedef __attribute__((ext_vector_type(4))) float f32x4;
typedef __attribute__((ext_vector_type(16))) float f32x16;

__device__ __forceinline__ unsigned short f2bf(float f) {
  union { float f; unsigned u; } v; v.f = f;
  unsigned r = (v.u + 0x7fffu + ((v.u >> 16) & 1u)) >> 16;
  return (unsigned short)r;
}
__device__ __forceinline__ float bf2f(unsigned short h) {
  union { unsigned u; float f; } v; v.u = ((unsigned)h) << 16;
  return v.f;
}

__device__ __forceinline__ void stage16(const unsigned short* g, unsigned short* l) {
  __builtin_amdgcn_global_load_lds(
      (const __attribute__((address_space(1))) void*)g,
      (__attribute__((address_space(3))) void*)l, 16, 0, 0);
}

// XOR-swizzled staging (verified 0 conflicts in R4/R5):
// LDS[row][blk] holds global granule blk^(row&7); FRAG compensates on read.
#define SRC_BLK(tid) (((tid) & 7) ^ (((tid) >> 3) & 7))
#define FRAG(buf, R, KB) (*(const bf16x8*)((buf) + (R) * 64 + (((KB) ^ ((R) & 7)) * 8)))

__device__ __forceinline__ float blk_sum256(float v, volatile float* sb) {
#pragma unroll
  for (int o = 32; o > 0; o >>= 1) v += __shfl_down(v, o, 64);
  __syncthreads();
  if ((threadIdx.x & 63) == 0) sb[threadIdx.x >> 6] = v;
  __syncthreads();
  return sb[0] + sb[1] + sb[2] + sb[3];
}

__global__ void zero_acc_k(float* acc) {
  if (threadIdx.x < 8) acc[threadIdx.x] = 0.f;
}

// ---------- row L2 normalize (both embeds) -> bf16 + post-norm sumsq ----------
__global__ __launch_bounds__(256) void rownorm_k(const float* __restrict__ xv,
                                                 const float* __restrict__ xt,
                                                 unsigned short* __restrict__ yv,
                                                 unsigned short* __restrict__ yt,
                                                 float* __restrict__ sqv,
                                                 float* __restrict__ sqt) {
  __shared__ float sb[4];
  const float* x = blockIdx.y ? xt : xv;
  unsigned short* y = blockIdx.y ? yt : yv;
  float* sq = blockIdx.y ? sqt : sqv;
  int r = blockIdx.x;
  const float* xr = x + (size_t)r * Dn;
  float s = 0.f;
  for (int k = threadIdx.x; k < Dn; k += 256) { float v = xr[k]; s += v * v; }
  s = blk_sum256(s, sb);
  float nrm = sqrtf(s);
  float s2 = 0.f;
  for (int k = threadIdx.x; k < Dn; k += 256) {
    float v = xr[k] / nrm;
    y[(size_t)r * Dn + k] = f2bf(v);
    s2 += v * v;
  }
  s2 = blk_sum256(s2, sb);
  if (threadIdx.x == 0) sq[r] = s2;
}

// ---------- column inverse-norms of W and W_text ----------
__global__ __launch_bounds__(256) void colnorm_k(const float* __restrict__ W,
                                                 const float* __restrict__ Wt,
                                                 float* __restrict__ rnW,
                                                 float* __restrict__ rnWt) {
  const float* X = blockIdx.y ? Wt : W;
  float* rn = blockIdx.y ? rnWt : rnW;
  int c = blockIdx.x * 256 + threadIdx.x;
  if (c >= Cn) return;
  float s = 0.f;
  for (int d = 0; d < Dn; ++d) { float v = X[(size_t)d * Cn + c]; s += v * v; }
  rn[c] = 1.f / sqrtf(s);
}

// ---------- transpose+normalize+bf16 (both weights) ----------
__global__ __launch_bounds__(256) void transpose_k(const float* __restrict__ W,
                                                   const float* __restrict__ Wt,
                                                   const float* __restrict__ rnW,
                                                   const float* __restrict__ rnWt,
                                                   unsigned short* __restrict__ WnT,
                                                   unsigned short* __restrict__ WtnT) {
  __shared__ float T[64][65];
  const float* X = blockIdx.z ? Wt : W;
  const float* rn = blockIdx.z ? rnWt : rnW;
  unsigned short* WT = blockIdx.z ? WtnT : WnT;
  const int c0 = blockIdx.x * 64, d0 = blockIdx.y * 64;
  const int tid = threadIdx.x;
  const int cl = tid & 63;
  for (int dl = tid >> 6; dl < 64; dl += 4) {
    float v = (c0 + cl < Cn) ? X[(size_t)(d0 + dl) * Cn + c0 + cl] : 0.f;
    T[cl][dl] = v;
  }
  __syncthreads();
  const int dd = tid & 63;
  for (int co = tid >> 6; co < 64; co += 4) {
    int c = c0 + co;
    unsigned short o = 0;
    if (c < Cn) o = f2bf(T[co][dd] * rn[c]);
    WT[(size_t)c * Dn + d0 + dd] = o;
  }
}

// ---------- dual logits GEMM (V,T) with 32x32x16 MFMA + 7 row quantities ----------
// Wave tile 64x64 = 2x2 of 32x32. C/D: col=lane&31, row=(r&3)+8*(r>>2)+4*(lane>>5).
__global__ __launch_bounds__(256, 2) void logits_vt_k(
    const unsigned short* __restrict__ vnh, const unsigned short* __restrict__ tnh,
    const unsigned short* __restrict__ WnT, float* __restrict__ part) {
  __shared__ __align__(16) unsigned short Av[128 * 64];
  __shared__ __align__(16) unsigned short At[128 * 64];
  __shared__ __align__(16) unsigned short Bs[128 * 64];
  __shared__ float qsum[7 * 128];

  const int rt = blockIdx.x, ct = blockIdx.y;
  const int r0 = rt * 128, c0 = ct * 128;
  const int tid = threadIdx.x;
  const int lane = tid & 63;
  const int wid = tid >> 6;
  const int wr = (wid >> 1) * 64, wc = (wid & 1) * 64;
  const int l31 = lane & 31, half = lane >> 5;

  for (int t = tid; t < 7 * 128; t += 256) qsum[t] = 0.f;

  f32x16 accV[2][2], accT[2][2];
#pragma unroll
  for (int i = 0; i < 2; ++i)
#pragma unroll
    for (int j = 0; j < 2; ++j)
#pragma unroll
      for (int e = 0; e < 16; ++e) { accV[i][j][e] = 0.f; accT[i][j][e] = 0.f; }

  const int srow = tid >> 3;
  const int skc = SRC_BLK(tid) * 8;

  for (int kk = 0; kk < 16; ++kk) {
    const int k0 = kk * 64;
#pragma unroll
    for (int p = 0; p < 4; ++p) {
      stage16(vnh + (size_t)(r0 + p * 32 + srow) * Dn + k0 + skc, Av + p * 2048 + tid * 8);
      stage16(tnh + (size_t)(r0 + p * 32 + srow) * Dn + k0 + skc, At + p * 2048 + tid * 8);
      stage16(WnT + (size_t)(c0 + p * 32 + srow) * Dn + k0 + skc, Bs + p * 2048 + tid * 8);
    }
    __syncthreads();
#pragma unroll
    for (int t = 0; t < 4; ++t) {  // K=16 steps
      const int KB = t * 2 + half;
      bf16x8 av[2], at[2], bb[2];
#pragma unroll
      for (int f = 0; f < 2; ++f) {
        av[f] = FRAG(Av, wr + f * 32 + l31, KB);
        at[f] = FRAG(At, wr + f * 32 + l31, KB);
        bb[f] = FRAG(Bs, wc + f * 32 + l31, KB);
      }
#pragma unroll
      for (int i = 0; i < 2; ++i)
#pragma unroll
        for (int j = 0; j < 2; ++j) {
          accV[i][j] = __builtin_amdgcn_mfma_f32_32x32x16_bf16(av[i], bb[j], accV[i][j], 0, 0, 0);
          accT[i][j] = __builtin_amdgcn_mfma_f32_32x32x16_bf16(at[i], bb[j], accT[i][j], 0, 0, 0);
        }
    }
    __syncthreads();
  }

  // epilogue: 7 per-row quantities; rows (r&3)+8*(r>>2)+4*half per 32x32 block
#pragma unroll
  for (int bi = 0; bi < 2; ++bi) {
#pragma unroll
    for (int r = 0; r < 16; ++r) {
      const int rowl = wr + bi * 32 + (r & 3) + 8 * (r >> 2) + 4 * half;
      float s0 = 0.f, s1 = 0.f, s2 = 0.f, s3 = 0.f, s6 = 0.f, s7 = 0.f, s8 = 0.f;
#pragma unroll
      for (int bj = 0; bj < 2; ++bj) {
        int col = c0 + wc + bj * 32 + l31;
        if (col < Cn) {
          float V = 28.f * accV[bi][bj][r];
          float T = 28.f * accT[bi][bj][r];
          float ev4 = __expf((V - 28.f) * 0.25f);
          float et4 = __expf((T - 28.f) * 0.25f);
          float ev2 = ev4 * ev4, et2 = et4 * et4;
          s0 += ev2 * ev2;
          s1 += V;
          s2 += et2 * et2;
          s3 += T;
          s6 += ev4;
          s7 += et4;
          s8 += ev4 * (V - T);
        }
      }
#pragma unroll
      for (int o = 1; o < 32; o <<= 1) {
        s0 += __shfl_xor(s0, o, 64); s1 += __shfl_xor(s1, o, 64);
        s2 += __shfl_xor(s2, o, 64); s3 += __shfl_xor(s3, o, 64);
        s6 += __shfl_xor(s6, o, 64); s7 += __shfl_xor(s7, o, 64);
        s8 += __shfl_xor(s8, o, 64);
      }
      if (l31 == 0) {
        atomicAdd(&qsum[0 * 128 + rowl], s0);
        atomicAdd(&qsum[1 * 128 + rowl], s1);
        atomicAdd(&qsum[2 * 128 + rowl], s2);
        atomicAdd(&qsum[3 * 128 + rowl], s3);
        atomicAdd(&qsum[4 * 128 + rowl], s6);
        atomicAdd(&qsum[5 * 128 + rowl], s7);
        atomicAdd(&qsum[6 * 128 + rowl], s8);
      }
    }
  }
  __syncthreads();
  if (tid < 128) {
    size_t base = (size_t)ct * Bn + r0 + tid;
    const size_t qs = (size_t)NCTL * Bn;
    part[0 * qs + base] = qsum[0 * 128 + tid];
    part[1 * qs + base] = qsum[1 * 128 + tid];
    part[2 * qs + base] = qsum[2 * 128 + tid];
    part[3 * qs + base] = qsum[3 * 128 + tid];
    part[6 * qs + base] = qsum[4 * 128 + tid];
    part[7 * qs + base] = qsum[5 * 128 + tid];
    part[8 * qs + base] = qsum[6 * 128 + tid];
  }
}

// ---------- filter logits GEMM (F), 256x128 tile, 32x32x16, wave 128x64 ----------
__global__ __launch_bounds__(256, 2) void logits_f_k(
    const unsigned short* __restrict__ tnh, const unsigned short* __restrict__ WtnT,
    float* __restrict__ part) {
  __shared__ __align__(16) unsigned short Aa[256 * 64];
  __shared__ __align__(16) unsigned short Bs[128 * 64];
  __shared__ float qsum[2 * 256];

  const int rt = blockIdx.x, ct = blockIdx.y;
  const int r0 = rt * 256, c0 = ct * 128;
  const int tid = threadIdx.x;
  const int lane = tid & 63;
  const int wid = tid >> 6;
  const int wr = (wid >> 1) * 128, wc = (wid & 1) * 64;
  const int l31 = lane & 31, half = lane >> 5;

  for (int t = tid; t < 2 * 256; t += 256) qsum[t] = 0.f;

  f32x16 acc[4][2];
#pragma unroll
  for (int i = 0; i < 4; ++i)
#pragma unroll
    for (int j = 0; j < 2; ++j)
#pragma unroll
      for (int e = 0; e < 16; ++e) acc[i][j][e] = 0.f;

  const int srow = tid >> 3;
  const int skc = SRC_BLK(tid) * 8;

  for (int kk = 0; kk < 16; ++kk) {
    const int k0 = kk * 64;
#pragma unroll
    for (int p = 0; p < 8; ++p)
      stage16(tnh + (size_t)(r0 + p * 32 + srow) * Dn + k0 + skc, Aa + p * 2048 + tid * 8);
#pragma unroll
    for (int p = 0; p < 4; ++p)
      stage16(WtnT + (size_t)(c0 + p * 32 + srow) * Dn + k0 + skc, Bs + p * 2048 + tid * 8);
    __syncthreads();
#pragma unroll
    for (int t = 0; t < 4; ++t) {
      const int KB = t * 2 + half;
      bf16x8 aa[4], bb[2];
#pragma unroll
      for (int f = 0; f < 4; ++f) aa[f] = FRAG(Aa, wr + f * 32 + l31, KB);
#pragma unroll
      for (int f = 0; f < 2; ++f) bb[f] = FRAG(Bs, wc + f * 32 + l31, KB);
#pragma unroll
      for (int i = 0; i < 4; ++i)
#pragma unroll
        for (int j = 0; j < 2; ++j)
          acc[i][j] = __builtin_amdgcn_mfma_f32_32x32x16_bf16(aa[i], bb[j], acc[i][j], 0, 0, 0);
    }
    __syncthreads();
  }

#pragma unroll
  for (int bi = 0; bi < 4; ++bi) {
#pragma unroll
    for (int r = 0; r < 16; ++r) {
      const int rowl = wr + bi * 32 + (r & 3) + 8 * (r >> 2) + 4 * half;
      float s4 = 0.f, s5 = 0.f;
#pragma unroll
      for (int bj = 0; bj < 2; ++bj) {
        int col = c0 + wc + bj * 32 + l31;
        if (col < Cn) {
          float F = 28.f * acc[bi][bj][r];
          s4 += __expf(F - 28.f);
          s5 += F;
        }
      }
#pragma unroll
      for (int o = 1; o < 32; o <<= 1) {
        s4 += __shfl_xor(s4, o, 64);
        s5 += __shfl_xor(s5, o, 64);
      }
      if (l31 == 0) {
        atomicAdd(&qsum[0 * 256 + rowl], s4);
        atomicAdd(&qsum[1 * 256 + rowl], s5);
      }
    }
  }
  __syncthreads();
  {
    size_t base = (size_t)ct * Bn + r0 + tid;
    const size_t qs = (size_t)NCTL * Bn;
    part[4 * qs + base] = qsum[0 * 256 + tid];
    part[5 * qs + base] = qsum[1 * 256 + tid];
  }
}

// ---------- fused: Gv = vi@vj^T (fp32 write) + align loss from vi@tj^T ----------
// Full grid; shares the vi A-tile between both products (2 acc sets = 32 f32x4, no spill).
__global__ __launch_bounds__(256, 2) void gramv_align_k(
    const unsigned short* __restrict__ vnh, const unsigned short* __restrict__ tnh,
    const int* __restrict__ labels, float* __restrict__ G, float* __restrict__ accbuf) {
  __shared__ __align__(16) unsigned short Aa[128 * 64];
  __shared__ __align__(16) unsigned short Vb[128 * 64];
  __shared__ __align__(16) unsigned short Tb[128 * 64];
  __shared__ int li_s[128], lj_s[128];
  __shared__ float sb[4];
  const int jt = blockIdx.x, it = blockIdx.y;
  const int j0 = jt * 128, i0 = it * 128;
  const int tid = threadIdx.x;
  const int lane = tid & 63;
  const int wid = tid >> 6;
  const int wr = (wid >> 1) * 64, wc = (wid & 1) * 64;
  const int m = lane & 15, q = lane >> 4;

  if (tid < 128) li_s[tid] = labels[i0 + tid];
  else lj_s[tid - 128] = labels[j0 + tid - 128];

  const f32x4 zero4 = {0.f, 0.f, 0.f, 0.f};
  f32x4 accG[4][4], accS[4][4];
#pragma unroll
  for (int i = 0; i < 4; ++i)
#pragma unroll
    for (int j = 0; j < 4; ++j) { accG[i][j] = zero4; accS[i][j] = zero4; }

  const int srow = tid >> 3;
  const int skc = SRC_BLK(tid) * 8;

  for (int kk = 0; kk < 16; ++kk) {
    const int k0 = kk * 64;
#pragma unroll
    for (int p = 0; p < 4; ++p) {
      stage16(vnh + (size_t)(i0 + p * 32 + srow) * Dn + k0 + skc, Aa + p * 2048 + tid * 8);
      stage16(vnh + (size_t)(j0 + p * 32 + srow) * Dn + k0 + skc, Vb + p * 2048 + tid * 8);
      stage16(tnh + (size_t)(j0 + p * 32 + srow) * Dn + k0 + skc, Tb + p * 2048 + tid * 8);
    }
    __syncthreads();
#pragma unroll
    for (int ks = 0; ks < 2; ++ks) {
      const int KB = ks * 4 + q;
      bf16x8 aa[4], vb[4], tb[4];
#pragma unroll
      for (int f = 0; f < 4; ++f) {
        aa[f] = FRAG(Aa, wr + f * 16 + m, KB);
        vb[f] = FRAG(Vb, wc + f * 16 + m, KB);
        tb[f] = FRAG(Tb, wc + f * 16 + m, KB);
      }
#pragma unroll
      for (int i = 0; i < 4; ++i)
#pragma unroll
        for (int j = 0; j < 4; ++j) {
          accG[i][j] = __builtin_amdgcn_mfma_f32_16x16x32_bf16(aa[i], vb[j], accG[i][j], 0, 0, 0);
          accS[i][j] = __builtin_amdgcn_mfma_f32_16x16x32_bf16(aa[i], tb[j], accS[i][j], 0, 0, 0);
        }
    }
    __syncthreads();
  }

  float ls = 0.f;
#pragma unroll
  for (int i = 0; i < 4; ++i)
#pragma unroll
    for (int r = 0; r < 4; ++r) {
      int rowl = wr + i * 16 + q * 4 + r;
      int li = li_s[rowl];
#pragma unroll
      for (int j = 0; j < 4; ++j) {
        int coll = wc + j * 16 + m;
        G[(size_t)(i0 + rowl) * Bn + j0 + coll] = accG[i][j][r];
        int lj = lj_s[coll];
        float s = accS[i][j][r];
        float x = (li == lj) ? (-10.f * (s - 0.6f)) : (40.f * (s - 0.4f));
        ls += fmaxf(x, 0.f) + __logf(1.f + __expf(-fabsf(x)));
      }
    }
  float tot = blk_sum256(ls, sb);
  if (tid == 0) atomicAdd(&accbuf[1], tot);
}

// ---------- symmetric gram (bf16 out): Gt = A@A^T, triangular + mirror ----------
__global__ __launch_bounds__(256, 3) void gramsym_bf16_k(const unsigned short* __restrict__ A,
                                                         unsigned short* __restrict__ G) {
  __shared__ __align__(16) unsigned short Aa[128 * 64];
  __shared__ __align__(16) unsigned short Bs[128 * 64];
  int t = blockIdx.x, it = 0, rem = NT;
  while (t >= rem) { t -= rem; ++it; --rem; }
  const int jt = it + t;
  const int i0 = it * 128, j0 = jt * 128;
  const int tid = threadIdx.x;
  const int lane = tid & 63;
  const int wid = tid >> 6;
  const int wr = (wid >> 1) * 64, wc = (wid & 1) * 64;
  const int m = lane & 15, q = lane >> 4;

  const f32x4 zero4 = {0.f, 0.f, 0.f, 0.f};
  f32x4 acc[4][4];
#pragma unroll
  for (int i = 0; i < 4; ++i)
#pragma unroll
    for (int j = 0; j < 4; ++j) acc[i][j] = zero4;

  const int srow = tid >> 3;
  const int skc = SRC_BLK(tid) * 8;

  for (int kk = 0; kk < 16; ++kk) {
    const int k0 = kk * 64;
#pragma unroll
    for (int p = 0; p < 4; ++p) {
      stage16(A + (size_t)(i0 + p * 32 + srow) * Dn + k0 + skc, Aa + p * 2048 + tid * 8);
      stage16(A + (size_t)(j0 + p * 32 + srow) * Dn + k0 + skc, Bs + p * 2048 + tid * 8);
    }
    __syncthreads();
#pragma unroll
    for (int ks = 0; ks < 2; ++ks) {
      const int KB = ks * 4 + q;
      bf16x8 aa[4], bb[4];
#pragma unroll
      for (int f = 0; f < 4; ++f) {
        aa[f] = FRAG(Aa, wr + f * 16 + m, KB);
        bb[f] = FRAG(Bs, wc + f * 16 + m, KB);
      }
#pragma unroll
      for (int i = 0; i < 4; ++i)
#pragma unroll
        for (int j = 0; j < 4; ++j)
          acc[i][j] = __builtin_amdgcn_mfma_f32_16x16x32_bf16(aa[i], bb[j], acc[i][j], 0, 0, 0);
    }
    __syncthreads();
  }
#pragma unroll
  for (int i = 0; i < 4; ++i)
#pragma unroll
    for (int j = 0; j < 4; ++j)
#pragma unroll
      for (int r = 0; r < 4; ++r) {
        int row = wr + i * 16 + q * 4 + r, col = wc + j * 16 + m;
        unsigned short h = f2bf(acc[i][j][r]);
        G[(size_t)(i0 + row) * Bn + j0 + col] = h;
        if (it != jt) G[(size_t)(j0 + col) * Bn + i0 + row] = h;
      }
}

// ---------- picked-label logits + feature-distance per row (bf16 inputs) ----------
__global__ __launch_bounds__(256) void picked_k(const unsigned short* __restrict__ vnh,
                                                const unsigned short* __restrict__ tnh,
                                                const unsigned short* __restrict__ WnT,
                                                const unsigned short* __restrict__ WtnT,
                                                const int* __restrict__ labels,
                                                float* __restrict__ pv, float* __restrict__ pt,
                                                float* __restrict__ pf, float* __restrict__ df) {
  __shared__ float sb[4];
  int r = blockIdx.x;
  int lab = labels[r];
  float spv = 0.f, spt = 0.f, spf = 0.f, sdf = 0.f;
  for (int k = threadIdx.x; k < Dn; k += 256) {
    float a = bf2f(vnh[(size_t)r * Dn + k]);
    float b = bf2f(tnh[(size_t)r * Dn + k]);
    float w = bf2f(WnT[(size_t)lab * Dn + k]);
    float wt = bf2f(WtnT[(size_t)lab * Dn + k]);
    spv += a * w;
    spt += b * w;
    spf += b * wt;
    float dd = a - b;
    sdf += dd * dd;
  }
  spv = blk_sum256(spv, sb);
  spt = blk_sum256(spt, sb);
  spf = blk_sum256(spf, sb);
  sdf = blk_sum256(sdf, sb);
  if (threadIdx.x == 0) {
    pv[r] = 28.f * spv;
    pt[r] = 28.f * spt;
    pf[r] = 28.f * spf;
    df[r] = sdf;
  }
}

// ---------- reduce partials + per-row CE/KL/dist ----------
__global__ __launch_bounds__(256) void finalize_k(const float* __restrict__ part,
                                                  const float* __restrict__ pv,
                                                  const float* __restrict__ pt,
                                                  const float* __restrict__ pf,
                                                  const float* __restrict__ df,
                                                  float* __restrict__ accbuf) {
  __shared__ float sb[4];
  int r = blockIdx.x * 256 + threadIdx.x;
  float s[NQ];
#pragma unroll
  for (int q = 0; q < NQ; ++q) s[q] = 0.f;
  const size_t qs = (size_t)NCTL * Bn;
  for (int ct = 0; ct < NCTL; ++ct) {
#pragma unroll
    for (int q = 0; q < NQ; ++q) s[q] += part[(size_t)q * qs + (size_t)ct * Bn + r];
  }
  float lseV = logf(s[0]) + 28.f;
  float lseT = logf(s[2]) + 28.f;
  float lseF = logf(s[4]) + 28.f;
  const float invC = 1.f / (float)Cn;
  float ceV = -(0.9f * (pv[r] - lseV) + 0.1f * invC * (s[1] - (float)Cn * lseV));
  float ceT = -(0.9f * (pt[r] - lseT) + 0.1f * invC * (s[3] - (float)Cn * lseT));
  float ceF = -(0.9f * (pf[r] - lseF) + 0.1f * invC * (s[5] - (float)Cn * lseF));
  float kl = s[8] / (4.f * s[6]) + logf(s[7]) - logf(s[6]);
  float row = ceV + ceT + ceF + kl + df[r];
  float tot = blk_sum256(row, sb);
  if (threadIdx.x == 0) atomicAdd(&accbuf[0], tot / (float)Bn);
}

// ---------- HardDarkRank: swizzled-LDS selection + Gt lookup ----------
__device__ __forceinline__ int kswz(int j) {
  return (j & ~63) | ((j ^ (j >> 6)) & 63);
}
__device__ __forceinline__ unsigned long long shflx_u64(unsigned long long v, int o) {
  int lo = __shfl_xor((int)(unsigned)v, o, 64);
  int hi = __shfl_xor((int)(unsigned)(v >> 32), o, 64);
  return ((unsigned long long)(unsigned)hi << 32) | (unsigned)lo;
}

__global__ __launch_bounds__(256) void hdr_k(const float* __restrict__ Gv,
                                             const unsigned short* __restrict__ Gtb,
                                             const float* __restrict__ sqv,
                                             const float* __restrict__ sqt,
                                             float* __restrict__ accbuf) {
  __shared__ float key[Bn];
  __shared__ int selIdx[64];
  __shared__ float selS[64];
  const int i = blockIdx.x, tid = threadIdx.x;
  const int lane = tid & 63, wid = tid >> 6;
  const float INF = __builtin_inff();
  float sqi = sqv[i];
  const float4* gv4 = (const float4*)(Gv + (size_t)i * Bn);
  const float4* sq4 = (const float4*)sqv;
  for (int j4 = tid; j4 < Bn / 4; j4 += 256) {
    float4 g = gv4[j4];
    float4 s = sq4[j4];
    int j = j4 * 4;
    key[kswz(j + 0)] = (j + 0 == i) ? INF : fmaxf(sqi + s.x - 2.f * g.x, 1e-12f);
    key[kswz(j + 1)] = (j + 1 == i) ? INF : fmaxf(sqi + s.y - 2.f * g.y, 1e-12f);
    key[kswz(j + 2)] = (j + 2 == i) ? INF : fmaxf(sqi + s.z - 2.f * g.z, 1e-12f);
    key[kswz(j + 3)] = (j + 3 == i) ? INF : fmaxf(sqi + s.w - 2.f * g.w, 1e-12f);
  }
  __syncthreads();

  if (wid == 0) {
    unsigned long long best = ~0ull;
    for (int k = 0; k < 64; ++k) {
      int j = k * 64 + lane;
      float v = key[kswz(j)];
      unsigned long long p = ((unsigned long long)__float_as_uint(v) << 32) | (unsigned)j;
      if (p < best) best = p;
    }
    for (int it = 0; it < 63; ++it) {
      unsigned long long w = best;
#pragma unroll
      for (int o = 32; o > 0; o >>= 1) {
        unsigned long long ow = shflx_u64(w, o);
        if (ow < w) w = ow;
      }
      int bj = (int)(unsigned)w;
      if (lane == 0) selIdx[it] = bj;
      int s = bj & 63;
      int kj = (lane << 6) | s;
      int sidx = kswz(kj);
      float kv = key[sidx];
      if (kj == bj) { kv = INF; key[sidx] = INF; }
      unsigned long long p = ((unsigned long long)__float_as_uint(kv) << 32) | (unsigned)kj;
#pragma unroll
      for (int o = 32; o > 0; o >>= 1) {
        unsigned long long op = shflx_u64(p, o);
        if (op < p) p = op;
      }
      if (lane == s) best = p;
    }
  }
  __syncthreads();

  if (tid < 63) {
    int j = selIdx[tid];
    float g = bf2f(Gtb[(size_t)i * Bn + j]);
    float d2 = fmaxf(sqt[i] + sqt[j] - 2.f * g, 1e-12f);
    selS[tid] = -3.f * sqrtf(d2) * d2;
  }
  __syncthreads();

  if (tid == 0) {
    float lse = selS[62];
    float loss = 0.f;
    for (int k = 61; k >= 0; --k) {
      float a = fmaxf(lse, selS[k]);
      lse = a + logf(__expf(lse - a) + __expf(selS[k] - a));
      loss += lse - selS[k];
    }
    atomicAdd(&accbuf[2], loss);
  }
}

__global__ void combine_k(const float* __restrict__ accbuf, float* __restrict__ out) {
  out[0] = accbuf[0] + (2.f / (float)Bn) * accbuf[1] + (0.1f / (float)Bn) * accbuf[2];
}

// ---------- launch ----------
extern "C" void kernel_launch(void* const* d_in, const int* in_sizes, int n_in,
                              void* d_out, int out_size, void* d_ws, size_t ws_size,
                              hipStream_t stream) {
  const float* ve = (const float*)d_in[0];
  const float* te = (const float*)d_in[1];
  const int* labels = (const int*)d_in[2];
  const float* W = (const float*)d_in[3];
  const float* Wt = (const float*)d_in[4];
  float* out = (float*)d_out;

  char* base = (char*)d_ws;
  size_t off = 0;
  unsigned short* vnh = (unsigned short*)(base + off);  off += (size_t)Bn * Dn * 2;
  unsigned short* tnh = (unsigned short*)(base + off);  off += (size_t)Bn * Dn * 2;
  unsigned short* WnT = (unsigned short*)(base + off);  off += (size_t)Cpad * Dn * 2;
  unsigned short* WtnT = (unsigned short*)(base + off); off += (size_t)Cpad * Dn * 2;
  float* Gv = (float*)(base + off);          off += (size_t)Bn * Bn * 4;
  unsigned short* Gtb = (unsigned short*)(base + off); off += (size_t)Bn * Bn * 2;
  float* part = (float*)(base + off);        off += (size_t)NQ * NCTL * Bn * 4;
  float* rnW = (float*)(base + off);         off += (size_t)Cpad * 4;
  float* rnWt = (float*)(base + off);        off += (size_t)Cpad * 4;
  float* sqv = (float*)(base + off);         off += (size_t)Bn * 4;
  float* sqt = (float*)(base + off);         off += (size_t)Bn * 4;
  float* pv = (float*)(base + off);          off += (size_t)Bn * 4;
  float* pt = (float*)(base + off);          off += (size_t)Bn * 4;
  float* pf = (float*)(base + off);          off += (size_t)Bn * 4;
  float* df = (float*)(base + off);          off += (size_t)Bn * 4;
  float* acc = (float*)(base + off);         off += 64;

  zero_acc_k<<<1, 64, 0, stream>>>(acc);
  rownorm_k<<<dim3(Bn, 2), 256, 0, stream>>>(ve, te, vnh, tnh, sqv, sqt);
  colnorm_k<<<dim3((Cn + 255) / 256, 2), 256, 0, stream>>>(W, Wt, rnW, rnWt);
  transpose_k<<<dim3(Cpad / 64, Dn / 64, 2), 256, 0, stream>>>(W, Wt, rnW, rnWt, WnT, WtnT);
  logits_vt_k<<<dim3(Bn / 128, NCTL), 256, 0, stream>>>(vnh, tnh, WnT, part);
  logits_f_k<<<dim3(Bn / 256, NCTL), 256, 0, stream>>>(tnh, WtnT, part);
  gramv_align_k<<<dim3(NT, NT), 256, 0, stream>>>(vnh, tnh, labels, Gv, acc);
  gramsym_bf16_k<<<NTRI, 256, 0, stream>>>(tnh, Gtb);
  picked_k<<<Bn, 256, 0, stream>>>(vnh, tnh, WnT, WtnT, labels, pv, pt, pf, df);
  finalize_k<<<Bn / 256, 256, 0, stream>>>(part, pv, pt, pf, df, acc);
  hdr_k<<<Bn, 256, 0, stream>>>(Gv, Gtb, sqv, sqt, acc);
  combine_k<<<1, 1, 0, stream>>>(acc, out);
}

// Round 7
// 862.199 us; speedup vs baseline: 1.1900x; 1.1900x over previous
//
#include <hip/hip_runtime.h>
#include <math.h>

#define Bn 4096
#define Dn 1024
#define Cn 11003
#define Cpad 11008
#define NCTL 86
#define NQ 6
#define NT 32
#define NTRI 528  // NT*(NT+1)/2

typedef __attribute__((ext_vector_type(8))) short bf16x8;
typedef __attribute__((ext_vector_type(4))) float f32x4;

__device__ __forceinline__ unsigned short f2bf(float f) {
  union { float f; unsigned u; } v; v.f = f;
  unsigned r = (v.u + 0x7fffu + ((v.u >> 16) & 1u)) >> 16;
  return (unsigned short)r;
}
__device__ __forceinline__ float bf2f(unsigned short h) {
  union { unsigned u; float f; } v; v.u = ((unsigned)h) << 16;
  return v.f;
}

__device__ __forceinline__ void stage16(const unsigned short* g, unsigned short* l) {
  __builtin_amdgcn_global_load_lds(
      (const __attribute__((address_space(1))) void*)g,
      (__attribute__((address_space(3))) void*)l, 16, 0, 0);
}

// XOR-swizzled staging (verified 0 conflicts with the 16x16 read pattern, R4/R5).
#define SRC_BLK(tid) (((tid) & 7) ^ (((tid) >> 3) & 7))
#define FRAG(buf, R, KB) (*(const bf16x8*)((buf) + (R) * 64 + (((KB) ^ ((R) & 7)) * 8)))

__device__ __forceinline__ float blk_sum256(float v, volatile float* sb) {
#pragma unroll
  for (int o = 32; o > 0; o >>= 1) v += __shfl_down(v, o, 64);
  __syncthreads();
  if ((threadIdx.x & 63) == 0) sb[threadIdx.x >> 6] = v;
  __syncthreads();
  return sb[0] + sb[1] + sb[2] + sb[3];
}

__global__ void zero_acc_k(float* acc, float* cw, float* cwt) {
  int tid = threadIdx.x;
  for (int i = tid; i < Dn; i += 256) { cw[i] = 0.f; cwt[i] = 0.f; }
  if (tid < 8) acc[tid] = 0.f;
}

// ---------- row L2 normalize (both embeds) -> bf16 + post-norm sumsq ----------
__global__ __launch_bounds__(256) void rownorm_k(const float* __restrict__ xv,
                                                 const float* __restrict__ xt,
                                                 unsigned short* __restrict__ yv,
                                                 unsigned short* __restrict__ yt,
                                                 float* __restrict__ sqv,
                                                 float* __restrict__ sqt) {
  __shared__ float sb[4];
  const float* x = blockIdx.y ? xt : xv;
  unsigned short* y = blockIdx.y ? yt : yv;
  float* sq = blockIdx.y ? sqt : sqv;
  int r = blockIdx.x;
  const float* xr = x + (size_t)r * Dn;
  float s = 0.f;
  for (int k = threadIdx.x; k < Dn; k += 256) { float v = xr[k]; s += v * v; }
  s = blk_sum256(s, sb);
  float nrm = sqrtf(s);
  float s2 = 0.f;
  for (int k = threadIdx.x; k < Dn; k += 256) {
    float v = xr[k] / nrm;
    y[(size_t)r * Dn + k] = f2bf(v);
    s2 += v * v;
  }
  s2 = blk_sum256(s2, sb);
  if (threadIdx.x == 0) sq[r] = s2;
}

// ---------- column inverse-norms of W and W_text ----------
__global__ __launch_bounds__(256) void colnorm_k(const float* __restrict__ W,
                                                 const float* __restrict__ Wt,
                                                 float* __restrict__ rnW,
                                                 float* __restrict__ rnWt) {
  const float* X = blockIdx.y ? Wt : W;
  float* rn = blockIdx.y ? rnWt : rnW;
  int c = blockIdx.x * 256 + threadIdx.x;
  if (c >= Cn) return;
  float s = 0.f;
  for (int d = 0; d < Dn; ++d) { float v = X[(size_t)d * Cn + c]; s += v * v; }
  rn[c] = 1.f / sqrtf(s);
}

// ---------- transpose+normalize+bf16 (both weights) + column-sum vectors ----------
// cw[d] = sum_c Wn[d][c] (quantized values), accumulated via LDS partials.
__global__ __launch_bounds__(256) void transpose_k(const float* __restrict__ W,
                                                   const float* __restrict__ Wt,
                                                   const float* __restrict__ rnW,
                                                   const float* __restrict__ rnWt,
                                                   unsigned short* __restrict__ WnT,
                                                   unsigned short* __restrict__ WtnT,
                                                   float* __restrict__ cw,
                                                   float* __restrict__ cwt) {
  __shared__ float T[64][65];
  __shared__ float cwp[64];
  const float* X = blockIdx.z ? Wt : W;
  const float* rn = blockIdx.z ? rnWt : rnW;
  unsigned short* WT = blockIdx.z ? WtnT : WnT;
  float* cwg = blockIdx.z ? cwt : cw;
  const int c0 = blockIdx.x * 64, d0 = blockIdx.y * 64;
  const int tid = threadIdx.x;
  const int cl = tid & 63;
  if (tid < 64) cwp[tid] = 0.f;
  for (int dl = tid >> 6; dl < 64; dl += 4) {
    float v = (c0 + cl < Cn) ? X[(size_t)(d0 + dl) * Cn + c0 + cl] : 0.f;
    T[cl][dl] = v;
  }
  __syncthreads();
  const int dd = tid & 63;
  float ls = 0.f;
  for (int co = tid >> 6; co < 64; co += 4) {
    int c = c0 + co;
    unsigned short o = 0;
    if (c < Cn) o = f2bf(T[co][dd] * rn[c]);
    WT[(size_t)c * Dn + d0 + dd] = o;
    ls += bf2f(o);
  }
  atomicAdd(&cwp[dd], ls);
  __syncthreads();
  if (tid < 64) atomicAdd(&cwg[d0 + tid], cwp[tid]);
}

// ---------- dual logits GEMM (V,T) 16x16x32, 128x128 tile + 5 row quantities ----------
// part slots: 0=SexpV 1=SexpT 3=Sev4 4=Set4 5=Sev4*(V-T)   (2=SexpF from logits_f_k)
__global__ __launch_bounds__(256, 2) void logits_vt_k(
    const unsigned short* __restrict__ vnh, const unsigned short* __restrict__ tnh,
    const unsigned short* __restrict__ WnT, float* __restrict__ part) {
  __shared__ __align__(16) unsigned short Av[128 * 64];
  __shared__ __align__(16) unsigned short At[128 * 64];
  __shared__ __align__(16) unsigned short Bs[128 * 64];
  __shared__ float qsum[5 * 128];

  const int rt = blockIdx.x, ct = blockIdx.y;
  const int r0 = rt * 128, c0 = ct * 128;
  const int tid = threadIdx.x;
  const int lane = tid & 63;
  const int wid = tid >> 6;
  const int wr = (wid >> 1) * 64, wc = (wid & 1) * 64;
  const int m = lane & 15, q = lane >> 4;

  for (int t = tid; t < 5 * 128; t += 256) qsum[t] = 0.f;

  const f32x4 zero4 = {0.f, 0.f, 0.f, 0.f};
  f32x4 accV[4][4], accT[4][4];
#pragma unroll
  for (int i = 0; i < 4; ++i)
#pragma unroll
    for (int j = 0; j < 4; ++j) { accV[i][j] = zero4; accT[i][j] = zero4; }

  const int srow = tid >> 3;
  const int skc = SRC_BLK(tid) * 8;

  for (int kk = 0; kk < 16; ++kk) {
    const int k0 = kk * 64;
#pragma unroll
    for (int p = 0; p < 4; ++p) {
      stage16(vnh + (size_t)(r0 + p * 32 + srow) * Dn + k0 + skc, Av + p * 2048 + tid * 8);
      stage16(tnh + (size_t)(r0 + p * 32 + srow) * Dn + k0 + skc, At + p * 2048 + tid * 8);
      stage16(WnT + (size_t)(c0 + p * 32 + srow) * Dn + k0 + skc, Bs + p * 2048 + tid * 8);
    }
    __syncthreads();
#pragma unroll
    for (int ks = 0; ks < 2; ++ks) {
      const int KB = ks * 4 + q;
      bf16x8 av[4], at[4], bb[4];
#pragma unroll
      for (int f = 0; f < 4; ++f) {
        av[f] = FRAG(Av, wr + f * 16 + m, KB);
        at[f] = FRAG(At, wr + f * 16 + m, KB);
        bb[f] = FRAG(Bs, wc + f * 16 + m, KB);
      }
#pragma unroll
      for (int i = 0; i < 4; ++i)
#pragma unroll
        for (int j = 0; j < 4; ++j) {
          accV[i][j] = __builtin_amdgcn_mfma_f32_16x16x32_bf16(av[i], bb[j], accV[i][j], 0, 0, 0);
          accT[i][j] = __builtin_amdgcn_mfma_f32_16x16x32_bf16(at[i], bb[j], accT[i][j], 0, 0, 0);
        }
    }
    __syncthreads();
  }

#pragma unroll
  for (int i = 0; i < 4; ++i) {
#pragma unroll
    for (int r = 0; r < 4; ++r) {
      const int rowl = wr + i * 16 + q * 4 + r;
      float s0 = 0.f, s2 = 0.f, s6 = 0.f, s7 = 0.f, s8 = 0.f;
#pragma unroll
      for (int j = 0; j < 4; ++j) {
        int col = c0 + wc + j * 16 + m;
        if (col < Cn) {
          float V = 28.f * accV[i][j][r];
          float T = 28.f * accT[i][j][r];
          float ev4 = __expf((V - 28.f) * 0.25f);
          float et4 = __expf((T - 28.f) * 0.25f);
          float ev2 = ev4 * ev4, et2 = et4 * et4;
          s0 += ev2 * ev2;
          s2 += et2 * et2;
          s6 += ev4;
          s7 += et4;
          s8 += ev4 * (V - T);
        }
      }
#pragma unroll
      for (int o = 1; o < 16; o <<= 1) {
        s0 += __shfl_xor(s0, o, 64); s2 += __shfl_xor(s2, o, 64);
        s6 += __shfl_xor(s6, o, 64); s7 += __shfl_xor(s7, o, 64);
        s8 += __shfl_xor(s8, o, 64);
      }
      if (m == 0) {
        atomicAdd(&qsum[0 * 128 + rowl], s0);
        atomicAdd(&qsum[1 * 128 + rowl], s2);
        atomicAdd(&qsum[2 * 128 + rowl], s6);
        atomicAdd(&qsum[3 * 128 + rowl], s7);
        atomicAdd(&qsum[4 * 128 + rowl], s8);
      }
    }
  }
  __syncthreads();
  if (tid < 128) {
    size_t base = (size_t)ct * Bn + r0 + tid;
    const size_t qs = (size_t)NCTL * Bn;
    part[0 * qs + base] = qsum[0 * 128 + tid];
    part[1 * qs + base] = qsum[1 * 128 + tid];
    part[3 * qs + base] = qsum[2 * 128 + tid];
    part[4 * qs + base] = qsum[3 * 128 + tid];
    part[5 * qs + base] = qsum[4 * 128 + tid];
  }
}

// ---------- filter logits GEMM (F = tn@Wtn), 256x128 tile, 1 row quantity ----------
__global__ __launch_bounds__(256, 2) void logits_f_k(
    const unsigned short* __restrict__ tnh, const unsigned short* __restrict__ WtnT,
    float* __restrict__ part) {
  __shared__ __align__(16) unsigned short Aa[256 * 64];
  __shared__ __align__(16) unsigned short Bs[128 * 64];
  __shared__ float qsum[256];

  const int rt = blockIdx.x, ct = blockIdx.y;
  const int r0 = rt * 256, c0 = ct * 128;
  const int tid = threadIdx.x;
  const int lane = tid & 63;
  const int wid = tid >> 6;
  const int wr = (wid >> 1) * 128, wc = (wid & 1) * 64;
  const int m = lane & 15, q = lane >> 4;

  qsum[tid] = 0.f;

  const f32x4 zero4 = {0.f, 0.f, 0.f, 0.f};
  f32x4 acc[8][4];
#pragma unroll
  for (int i = 0; i < 8; ++i)
#pragma unroll
    for (int j = 0; j < 4; ++j) acc[i][j] = zero4;

  const int srow = tid >> 3;
  const int skc = SRC_BLK(tid) * 8;

  for (int kk = 0; kk < 16; ++kk) {
    const int k0 = kk * 64;
#pragma unroll
    for (int p = 0; p < 8; ++p)
      stage16(tnh + (size_t)(r0 + p * 32 + srow) * Dn + k0 + skc, Aa + p * 2048 + tid * 8);
#pragma unroll
    for (int p = 0; p < 4; ++p)
      stage16(WtnT + (size_t)(c0 + p * 32 + srow) * Dn + k0 + skc, Bs + p * 2048 + tid * 8);
    __syncthreads();
#pragma unroll
    for (int ks = 0; ks < 2; ++ks) {
      const int KB = ks * 4 + q;
      bf16x8 aa[8], bb[4];
#pragma unroll
      for (int f = 0; f < 8; ++f) aa[f] = FRAG(Aa, wr + f * 16 + m, KB);
#pragma unroll
      for (int f = 0; f < 4; ++f) bb[f] = FRAG(Bs, wc + f * 16 + m, KB);
#pragma unroll
      for (int i = 0; i < 8; ++i)
#pragma unroll
        for (int j = 0; j < 4; ++j)
          acc[i][j] = __builtin_amdgcn_mfma_f32_16x16x32_bf16(aa[i], bb[j], acc[i][j], 0, 0, 0);
    }
    __syncthreads();
  }

#pragma unroll
  for (int i = 0; i < 8; ++i) {
#pragma unroll
    for (int r = 0; r < 4; ++r) {
      const int rowl = wr + i * 16 + q * 4 + r;
      float s4 = 0.f;
#pragma unroll
      for (int j = 0; j < 4; ++j) {
        int col = c0 + wc + j * 16 + m;
        if (col < Cn) s4 += __expf(28.f * acc[i][j][r] - 28.f);
      }
#pragma unroll
      for (int o = 1; o < 16; o <<= 1) s4 += __shfl_xor(s4, o, 64);
      if (m == 0) atomicAdd(&qsum[rowl], s4);
    }
  }
  __syncthreads();
  {
    size_t base = (size_t)ct * Bn + r0 + tid;
    const size_t qs = (size_t)NCTL * Bn;
    part[2 * qs + base] = qsum[tid];
  }
}

// ---------- fused: Gv = vi@vj^T (fp32 write) + align loss from vi@tj^T ----------
__global__ __launch_bounds__(256, 2) void gramv_align_k(
    const unsigned short* __restrict__ vnh, const unsigned short* __restrict__ tnh,
    const int* __restrict__ labels, float* __restrict__ G, float* __restrict__ accbuf) {
  __shared__ __align__(16) unsigned short Aa[128 * 64];
  __shared__ __align__(16) unsigned short Vb[128 * 64];
  __shared__ __align__(16) unsigned short Tb[128 * 64];
  __shared__ int li_s[128], lj_s[128];
  __shared__ float sb[4];
  const int jt = blockIdx.x, it = blockIdx.y;
  const int j0 = jt * 128, i0 = it * 128;
  const int tid = threadIdx.x;
  const int lane = tid & 63;
  const int wid = tid >> 6;
  const int wr = (wid >> 1) * 64, wc = (wid & 1) * 64;
  const int m = lane & 15, q = lane >> 4;

  if (tid < 128) li_s[tid] = labels[i0 + tid];
  else lj_s[tid - 128] = labels[j0 + tid - 128];

  const f32x4 zero4 = {0.f, 0.f, 0.f, 0.f};
  f32x4 accG[4][4], accS[4][4];
#pragma unroll
  for (int i = 0; i < 4; ++i)
#pragma unroll
    for (int j = 0; j < 4; ++j) { accG[i][j] = zero4; accS[i][j] = zero4; }

  const int srow = tid >> 3;
  const int skc = SRC_BLK(tid) * 8;

  for (int kk = 0; kk < 16; ++kk) {
    const int k0 = kk * 64;
#pragma unroll
    for (int p = 0; p < 4; ++p) {
      stage16(vnh + (size_t)(i0 + p * 32 + srow) * Dn + k0 + skc, Aa + p * 2048 + tid * 8);
      stage16(vnh + (size_t)(j0 + p * 32 + srow) * Dn + k0 + skc, Vb + p * 2048 + tid * 8);
      stage16(tnh + (size_t)(j0 + p * 32 + srow) * Dn + k0 + skc, Tb + p * 2048 + tid * 8);
    }
    __syncthreads();
#pragma unroll
    for (int ks = 0; ks < 2; ++ks) {
      const int KB = ks * 4 + q;
      bf16x8 aa[4], vb[4], tb[4];
#pragma unroll
      for (int f = 0; f < 4; ++f) {
        aa[f] = FRAG(Aa, wr + f * 16 + m, KB);
        vb[f] = FRAG(Vb, wc + f * 16 + m, KB);
        tb[f] = FRAG(Tb, wc + f * 16 + m, KB);
      }
#pragma unroll
      for (int i = 0; i < 4; ++i)
#pragma unroll
        for (int j = 0; j < 4; ++j) {
          accG[i][j] = __builtin_amdgcn_mfma_f32_16x16x32_bf16(aa[i], vb[j], accG[i][j], 0, 0, 0);
          accS[i][j] = __builtin_amdgcn_mfma_f32_16x16x32_bf16(aa[i], tb[j], accS[i][j], 0, 0, 0);
        }
    }
    __syncthreads();
  }

  float ls = 0.f;
#pragma unroll
  for (int i = 0; i < 4; ++i)
#pragma unroll
    for (int r = 0; r < 4; ++r) {
      int rowl = wr + i * 16 + q * 4 + r;
      int li = li_s[rowl];
#pragma unroll
      for (int j = 0; j < 4; ++j) {
        int coll = wc + j * 16 + m;
        G[(size_t)(i0 + rowl) * Bn + j0 + coll] = accG[i][j][r];
        int lj = lj_s[coll];
        float s = accS[i][j][r];
        float x = (li == lj) ? (-10.f * (s - 0.6f)) : (40.f * (s - 0.4f));
        ls += fmaxf(x, 0.f) + __logf(1.f + __expf(-fabsf(x)));
      }
    }
  float tot = blk_sum256(ls, sb);
  if (tid == 0) atomicAdd(&accbuf[1], tot);
}

// ---------- symmetric gram (bf16 out): Gt = A@A^T, triangular + mirror ----------
__global__ __launch_bounds__(256, 3) void gramsym_bf16_k(const unsigned short* __restrict__ A,
                                                         unsigned short* __restrict__ G) {
  __shared__ __align__(16) unsigned short Aa[128 * 64];
  __shared__ __align__(16) unsigned short Bs[128 * 64];
  int t = blockIdx.x, it = 0, rem = NT;
  while (t >= rem) { t -= rem; ++it; --rem; }
  const int jt = it + t;
  const int i0 = it * 128, j0 = jt * 128;
  const int tid = threadIdx.x;
  const int lane = tid & 63;
  const int wid = tid >> 6;
  const int wr = (wid >> 1) * 64, wc = (wid & 1) * 64;
  const int m = lane & 15, q = lane >> 4;

  const f32x4 zero4 = {0.f, 0.f, 0.f, 0.f};
  f32x4 acc[4][4];
#pragma unroll
  for (int i = 0; i < 4; ++i)
#pragma unroll
    for (int j = 0; j < 4; ++j) acc[i][j] = zero4;

  const int srow = tid >> 3;
  const int skc = SRC_BLK(tid) * 8;

  for (int kk = 0; kk < 16; ++kk) {
    const int k0 = kk * 64;
#pragma unroll
    for (int p = 0; p < 4; ++p) {
      stage16(A + (size_t)(i0 + p * 32 + srow) * Dn + k0 + skc, Aa + p * 2048 + tid * 8);
      stage16(A + (size_t)(j0 + p * 32 + srow) * Dn + k0 + skc, Bs + p * 2048 + tid * 8);
    }
    __syncthreads();
#pragma unroll
    for (int ks = 0; ks < 2; ++ks) {
      const int KB = ks * 4 + q;
      bf16x8 aa[4], bb[4];
#pragma unroll
      for (int f = 0; f < 4; ++f) {
        aa[f] = FRAG(Aa, wr + f * 16 + m, KB);
        bb[f] = FRAG(Bs, wc + f * 16 + m, KB);
      }
#pragma unroll
      for (int i = 0; i < 4; ++i)
#pragma unroll
        for (int j = 0; j < 4; ++j)
          acc[i][j] = __builtin_amdgcn_mfma_f32_16x16x32_bf16(aa[i], bb[j], acc[i][j], 0, 0, 0);
    }
    __syncthreads();
  }
#pragma unroll
  for (int i = 0; i < 4; ++i)
#pragma unroll
    for (int j = 0; j < 4; ++j)
#pragma unroll
      for (int r = 0; r < 4; ++r) {
        int row = wr + i * 16 + q * 4 + r, col = wc + j * 16 + m;
        unsigned short h = f2bf(acc[i][j][r]);
        G[(size_t)(i0 + row) * Bn + j0 + col] = h;
        if (it != jt) G[(size_t)(j0 + col) * Bn + i0 + row] = h;
      }
}

// ---------- picked-label logits + feature-distance + plain-logit sums ----------
__global__ __launch_bounds__(256) void picked_k(const unsigned short* __restrict__ vnh,
                                                const unsigned short* __restrict__ tnh,
                                                const unsigned short* __restrict__ WnT,
                                                const unsigned short* __restrict__ WtnT,
                                                const float* __restrict__ cw,
                                                const float* __restrict__ cwt,
                                                const int* __restrict__ labels,
                                                float* __restrict__ pv, float* __restrict__ pt,
                                                float* __restrict__ pf, float* __restrict__ df,
                                                float* __restrict__ sv, float* __restrict__ st,
                                                float* __restrict__ sf) {
  __shared__ float sb[4];
  int r = blockIdx.x;
  int lab = labels[r];
  float spv = 0.f, spt = 0.f, spf = 0.f, sdf = 0.f, ssv = 0.f, sst = 0.f, ssf = 0.f;
  for (int k = threadIdx.x; k < Dn; k += 256) {
    float a = bf2f(vnh[(size_t)r * Dn + k]);
    float b = bf2f(tnh[(size_t)r * Dn + k]);
    float w = bf2f(WnT[(size_t)lab * Dn + k]);
    float wt = bf2f(WtnT[(size_t)lab * Dn + k]);
    float c1 = cw[k], c2 = cwt[k];
    spv += a * w;
    spt += b * w;
    spf += b * wt;
    float dd = a - b;
    sdf += dd * dd;
    ssv += a * c1;
    sst += b * c1;
    ssf += b * c2;
  }
  spv = blk_sum256(spv, sb);
  spt = blk_sum256(spt, sb);
  spf = blk_sum256(spf, sb);
  sdf = blk_sum256(sdf, sb);
  ssv = blk_sum256(ssv, sb);
  sst = blk_sum256(sst, sb);
  ssf = blk_sum256(ssf, sb);
  if (threadIdx.x == 0) {
    pv[r] = 28.f * spv;
    pt[r] = 28.f * spt;
    pf[r] = 28.f * spf;
    df[r] = sdf;
    sv[r] = 28.f * ssv;
    st[r] = 28.f * sst;
    sf[r] = 28.f * ssf;
  }
}

// ---------- reduce partials + per-row CE/KL/dist ----------
__global__ __launch_bounds__(256) void finalize_k(const float* __restrict__ part,
                                                  const float* __restrict__ pv,
                                                  const float* __restrict__ pt,
                                                  const float* __restrict__ pf,
                                                  const float* __restrict__ df,
                                                  const float* __restrict__ sv,
                                                  const float* __restrict__ st,
                                                  const float* __restrict__ sf,
                                                  float* __restrict__ accbuf) {
  __shared__ float sb[4];
  int r = blockIdx.x * 256 + threadIdx.x;
  float s[NQ];
#pragma unroll
  for (int q = 0; q < NQ; ++q) s[q] = 0.f;
  const size_t qs = (size_t)NCTL * Bn;
  for (int ct = 0; ct < NCTL; ++ct) {
#pragma unroll
    for (int q = 0; q < NQ; ++q) s[q] += part[(size_t)q * qs + (size_t)ct * Bn + r];
  }
  // slots: 0=SexpV 1=SexpT 2=SexpF 3=Sev4 4=Set4 5=Sev4(V-T)
  float lseV = logf(s[0]) + 28.f;
  float lseT = logf(s[1]) + 28.f;
  float lseF = logf(s[2]) + 28.f;
  const float invC = 1.f / (float)Cn;
  float ceV = -(0.9f * (pv[r] - lseV) + 0.1f * invC * (sv[r] - (float)Cn * lseV));
  float ceT = -(0.9f * (pt[r] - lseT) + 0.1f * invC * (st[r] - (float)Cn * lseT));
  float ceF = -(0.9f * (pf[r] - lseF) + 0.1f * invC * (sf[r] - (float)Cn * lseF));
  float kl = s[5] / (4.f * s[3]) + logf(s[4]) - logf(s[3]);
  float row = ceV + ceT + ceF + kl + df[r];
  float tot = blk_sum256(row, sb);
  if (threadIdx.x == 0) atomicAdd(&accbuf[0], tot / (float)Bn);
}

// ---------- HardDarkRank: swizzled-LDS selection + Gt lookup ----------
__device__ __forceinline__ int kswz(int j) {
  return (j & ~63) | ((j ^ (j >> 6)) & 63);
}
__device__ __forceinline__ unsigned long long shflx_u64(unsigned long long v, int o) {
  int lo = __shfl_xor((int)(unsigned)v, o, 64);
  int hi = __shfl_xor((int)(unsigned)(v >> 32), o, 64);
  return ((unsigned long long)(unsigned)hi << 32) | (unsigned)lo;
}

__global__ __launch_bounds__(256) void hdr_k(const float* __restrict__ Gv,
                                             const unsigned short* __restrict__ Gtb,
                                             const float* __restrict__ sqv,
                                             const float* __restrict__ sqt,
                                             float* __restrict__ accbuf) {
  __shared__ float key[Bn];
  __shared__ int selIdx[64];
  __shared__ float selS[64];
  const int i = blockIdx.x, tid = threadIdx.x;
  const int lane = tid & 63, wid = tid >> 6;
  const float INF = __builtin_inff();
  float sqi = sqv[i];
  const float4* gv4 = (const float4*)(Gv + (size_t)i * Bn);
  const float4* sq4 = (const float4*)sqv;
  for (int j4 = tid; j4 < Bn / 4; j4 += 256) {
    float4 g = gv4[j4];
    float4 s = sq4[j4];
    int j = j4 * 4;
    key[kswz(j + 0)] = (j + 0 == i) ? INF : fmaxf(sqi + s.x - 2.f * g.x, 1e-12f);
    key[kswz(j + 1)] = (j + 1 == i) ? INF : fmaxf(sqi + s.y - 2.f * g.y, 1e-12f);
    key[kswz(j + 2)] = (j + 2 == i) ? INF : fmaxf(sqi + s.z - 2.f * g.z, 1e-12f);
    key[kswz(j + 3)] = (j + 3 == i) ? INF : fmaxf(sqi + s.w - 2.f * g.w, 1e-12f);
  }
  __syncthreads();

  if (wid == 0) {
    unsigned long long best = ~0ull;
    for (int k = 0; k < 64; ++k) {
      int j = k * 64 + lane;
      float v = key[kswz(j)];
      unsigned long long p = ((unsigned long long)__float_as_uint(v) << 32) | (unsigned)j;
      if (p < best) best = p;
    }
    for (int it = 0; it < 63; ++it) {
      unsigned long long w = best;
#pragma unroll
      for (int o = 32; o > 0; o >>= 1) {
        unsigned long long ow = shflx_u64(w, o);
        if (ow < w) w = ow;
      }
      int bj = (int)(unsigned)w;
      if (lane == 0) selIdx[it] = bj;
      int s = bj & 63;
      int kj = (lane << 6) | s;
      int sidx = kswz(kj);
      float kv = key[sidx];
      if (kj == bj) { kv = INF; key[sidx] = INF; }
      unsigned long long p = ((unsigned long long)__float_as_uint(kv) << 32) | (unsigned)kj;
#pragma unroll
      for (int o = 32; o > 0; o >>= 1) {
        unsigned long long op = shflx_u64(p, o);
        if (op < p) p = op;
      }
      if (lane == s) best = p;
    }
  }
  __syncthreads();

  if (tid < 63) {
    int j = selIdx[tid];
    float g = bf2f(Gtb[(size_t)i * Bn + j]);
    float d2 = fmaxf(sqt[i] + sqt[j] - 2.f * g, 1e-12f);
    selS[tid] = -3.f * sqrtf(d2) * d2;
  }
  __syncthreads();

  if (tid == 0) {
    float lse = selS[62];
    float loss = 0.f;
    for (int k = 61; k >= 0; --k) {
      float a = fmaxf(lse, selS[k]);
      lse = a + logf(__expf(lse - a) + __expf(selS[k] - a));
      loss += lse - selS[k];
    }
    atomicAdd(&accbuf[2], loss);
  }
}

__global__ void combine_k(const float* __restrict__ accbuf, float* __restrict__ out) {
  out[0] = accbuf[0] + (2.f / (float)Bn) * accbuf[1] + (0.1f / (float)Bn) * accbuf[2];
}

// ---------- launch ----------
extern "C" void kernel_launch(void* const* d_in, const int* in_sizes, int n_in,
                              void* d_out, int out_size, void* d_ws, size_t ws_size,
                              hipStream_t stream) {
  const float* ve = (const float*)d_in[0];
  const float* te = (const float*)d_in[1];
  const int* labels = (const int*)d_in[2];
  const float* W = (const float*)d_in[3];
  const float* Wt = (const float*)d_in[4];
  float* out = (float*)d_out;

  char* base = (char*)d_ws;
  size_t off = 0;
  unsigned short* vnh = (unsigned short*)(base + off);  off += (size_t)Bn * Dn * 2;
  unsigned short* tnh = (unsigned short*)(base + off);  off += (size_t)Bn * Dn * 2;
  unsigned short* WnT = (unsigned short*)(base + off);  off += (size_t)Cpad * Dn * 2;
  unsigned short* WtnT = (unsigned short*)(base + off); off += (size_t)Cpad * Dn * 2;
  float* Gv = (float*)(base + off);          off += (size_t)Bn * Bn * 4;
  unsigned short* Gtb = (unsigned short*)(base + off); off += (size_t)Bn * Bn * 2;
  float* part = (float*)(base + off);        off += (size_t)NQ * NCTL * Bn * 4;
  float* rnW = (float*)(base + off);         off += (size_t)Cpad * 4;
  float* rnWt = (float*)(base + off);        off += (size_t)Cpad * 4;
  float* cw = (float*)(base + off);          off += (size_t)Dn * 4;
  float* cwt = (float*)(base + off);         off += (size_t)Dn * 4;
  float* sqv = (float*)(base + off);         off += (size_t)Bn * 4;
  float* sqt = (float*)(base + off);         off += (size_t)Bn * 4;
  float* pv = (float*)(base + off);          off += (size_t)Bn * 4;
  float* pt = (float*)(base + off);          off += (size_t)Bn * 4;
  float* pf = (float*)(base + off);          off += (size_t)Bn * 4;
  float* df = (float*)(base + off);          off += (size_t)Bn * 4;
  float* sv = (float*)(base + off);          off += (size_t)Bn * 4;
  float* st = (float*)(base + off);          off += (size_t)Bn * 4;
  float* sf = (float*)(base + off);          off += (size_t)Bn * 4;
  float* acc = (float*)(base + off);         off += 64;

  zero_acc_k<<<1, 256, 0, stream>>>(acc, cw, cwt);
  rownorm_k<<<dim3(Bn, 2), 256, 0, stream>>>(ve, te, vnh, tnh, sqv, sqt);
  colnorm_k<<<dim3((Cn + 255) / 256, 2), 256, 0, stream>>>(W, Wt, rnW, rnWt);
  transpose_k<<<dim3(Cpad / 64, Dn / 64, 2), 256, 0, stream>>>(W, Wt, rnW, rnWt, WnT, WtnT, cw, cwt);
  logits_vt_k<<<dim3(Bn / 128, NCTL), 256, 0, stream>>>(vnh, tnh, WnT, part);
  logits_f_k<<<dim3(Bn / 256, NCTL), 256, 0, stream>>>(tnh, WtnT, part);
  gramv_align_k<<<dim3(NT, NT), 256, 0, stream>>>(vnh, tnh, labels, Gv, acc);
  gramsym_bf16_k<<<NTRI, 256, 0, stream>>>(tnh, Gtb);
  picked_k<<<Bn, 256, 0, stream>>>(vnh, tnh, WnT, WtnT, cw, cwt, labels, pv, pt, pf, df, sv, st, sf);
  finalize_k<<<Bn / 256, 256, 0, stream>>>(part, pv, pt, pf, df, sv, st, sf, acc);
  hdr_k<<<Bn, 256, 0, stream>>>(Gv, Gtb, sqv, sqt, acc);
  combine_k<<<1, 1, 0, stream>>>(acc, out);
}